// Round 6
// baseline (645.864 us; speedup 1.0000x reference)
//
#include <hip/hip_runtime.h>
#include <hip/hip_bf16.h>

#define NNODES 20000
#define NEDGES 640000
#define NB 50
#define NF 128

typedef unsigned int uint_t;
typedef unsigned short ushort_t;

typedef __bf16 bf16x8 __attribute__((ext_vector_type(8)));
typedef float f32x4 __attribute__((ext_vector_type(4)));

__device__ __forceinline__ float lo16(uint_t u) { return __uint_as_float(u << 16); }
__device__ __forceinline__ float hi16(uint_t u) { return __uint_as_float(u & 0xffff0000u); }

// fp32 -> bf16 bits (round to nearest even), returned in low 16 bits
__device__ __forceinline__ uint_t f2bf(float f) {
    uint_t u = __float_as_uint(f);
    return (u + 0x7fffu + ((u >> 16) & 1u)) >> 16;
}

// fast shifted softplus: hardware v_exp_f32 / v_log_f32
__device__ __forceinline__ float ssp_f(float x) {
    float t = __expf(-fabsf(x));
    return fmaxf(x, 0.0f) + __logf(1.0f + t) - 0.6931471805599453f;
}

// ---------------- zero agg (fallback path only, capture-safe) ----------------
__global__ __launch_bounds__(256) void k_zero(float4* __restrict__ p) {
    int i = blockIdx.x * 256 + threadIdx.x;   // 2500*256*16B = 10.24 MB exactly
    p[i] = make_float4(0.f, 0.f, 0.f, 0.f);
}

// ---------------- zero hist + cnt (40000 ints) ----------------
__global__ __launch_bounds__(256) void k_zero_small(int* __restrict__ p, int n) {
    int i = blockIdx.x * 256 + threadIdx.x;
    if (i < n) p[i] = 0;
}

// ---------------- histogram of dst ----------------
__global__ __launch_bounds__(256) void k_hist(const int* __restrict__ dst, int* __restrict__ hist) {
    int i = blockIdx.x * 256 + threadIdx.x;
    if (i < NEDGES) atomicAdd(&hist[dst[i]], 1);
}

// ---------------- single-block exclusive scan over NNODES bins ----------------
__global__ __launch_bounds__(1024) void k_scan(const int* __restrict__ hist, int* __restrict__ off) {
    __shared__ int buf[1024];
    __shared__ int carry;
    if (threadIdx.x == 0) carry = 0;
    __syncthreads();
    for (int base = 0; base < NNODES; base += 1024) {
        int i = base + (int)threadIdx.x;
        int v = (i < NNODES) ? hist[i] : 0;
        buf[threadIdx.x] = v;
        __syncthreads();
        for (int s = 1; s < 1024; s <<= 1) {
            int t = (threadIdx.x >= (unsigned)s) ? buf[threadIdx.x - s] : 0;
            __syncthreads();
            buf[threadIdx.x] += t;
            __syncthreads();
        }
        if (i < NNODES) off[i] = carry + buf[threadIdx.x] - v;
        __syncthreads();
        if (threadIdx.x == 1023) carry += buf[1023];
        __syncthreads();
    }
    if (threadIdx.x == 0) off[NNODES] = NEDGES;
}

// ---------------- scatter edge ids into dst-grouped perm ----------------
__global__ __launch_bounds__(256) void k_scatter(const int* __restrict__ dst,
                                                 const int* __restrict__ off,
                                                 int* __restrict__ cnt,
                                                 int* __restrict__ perm) {
    int i = blockIdx.x * 256 + threadIdx.x;
    if (i < NEDGES) {
        int d = dst[i];
        int pos = off[d] + atomicAdd(&cnt[d], 1);
        perm[pos] = i;
    }
}

// ---------------- segment-sum: agg[n] = sum over n's edges of msg[perm[p]] ----------------
__global__ __launch_bounds__(256) void k_agg(const int* __restrict__ off,
                                             const int* __restrict__ perm,
                                             const ushort_t* __restrict__ msg,
                                             float* __restrict__ agg) {
    int node = blockIdx.x * 4 + (threadIdx.x >> 6);
    int lane = threadIdx.x & 63;
    if (node >= NNODES) return;
    int s = off[node], e = off[node + 1];
    float a0 = 0.f, a1 = 0.f;
    #pragma unroll 4
    for (int p = s; p < e; ++p) {
        uint_t u = reinterpret_cast<const uint_t*>(msg)[(size_t)perm[p] * 64 + lane];
        a0 += lo16(u);
        a1 += hi16(u);
    }
    agg[(size_t)node * NF + 2 * lane]     = a0;
    agg[(size_t)node * NF + 2 * lane + 1] = a1;
}

// ---------------- node GEMM: Y = X @ W  (MFMA, 64-row tile) ----------------
__global__ __launch_bounds__(256) void k_node1(const float* __restrict__ X,
                                               const float* __restrict__ W,
                                               float* __restrict__ Y, int nrows)
{
    __shared__ alignas(16) ushort_t sx[64 * 136];
    const int tid  = threadIdx.x;
    const int wv   = tid >> 6, lane = tid & 63;
    const int col  = lane & 15, quad = lane >> 4;

    bf16x8 wf[2][4];
    #pragma unroll
    for (int nt = 0; nt < 2; ++nt) {
        int n = wv * 32 + nt * 16 + col;
        #pragma unroll
        for (int kc = 0; kc < 4; ++kc)
            #pragma unroll
            for (int j = 0; j < 8; ++j)
                wf[nt][kc][j] = (__bf16)W[(kc * 32 + quad * 8 + j) * NF + n];
    }

    const int rbase = blockIdx.x * 64;
    for (int i = tid; i < 64 * 64; i += 256) {
        int r = i >> 6, c = i & 63;
        int gr = rbase + r;
        float2 v = (gr < nrows) ? *reinterpret_cast<const float2*>(&X[(size_t)gr * NF + 2 * c])
                                : make_float2(0.f, 0.f);
        reinterpret_cast<uint_t*>(sx)[r * 68 + c] = f2bf(v.x) | (f2bf(v.y) << 16);
    }
    __syncthreads();

    f32x4 acc[4][2] = {};
    #pragma unroll
    for (int kc = 0; kc < 4; ++kc) {
        bf16x8 af[4];
        #pragma unroll
        for (int mt = 0; mt < 4; ++mt)
            af[mt] = *reinterpret_cast<const bf16x8*>(&sx[(mt * 16 + col) * 136 + kc * 32 + quad * 8]);
        #pragma unroll
        for (int mt = 0; mt < 4; ++mt)
            #pragma unroll
            for (int nt = 0; nt < 2; ++nt)
                acc[mt][nt] = __builtin_amdgcn_mfma_f32_16x16x32_bf16(af[mt], wf[nt][kc], acc[mt][nt], 0, 0, 0);
    }
    #pragma unroll
    for (int mt = 0; mt < 4; ++mt)
        #pragma unroll
        for (int nt = 0; nt < 2; ++nt)
            #pragma unroll
            for (int r = 0; r < 4; ++r) {
                int row = rbase + mt * 16 + quad * 4 + r;
                if (row < nrows) Y[(size_t)row * NF + wv * 32 + nt * 16 + col] = acc[mt][nt][r];
            }
}

// ---------------- fused tail: out = ssp(X @ W1 + b1) @ W2 + b2 ----------------
__global__ __launch_bounds__(256) void k_tail(const float* __restrict__ X,
                                              const float* __restrict__ W1, const float* __restrict__ B1,
                                              const float* __restrict__ W2, const float* __restrict__ B2,
                                              float* __restrict__ Y, int nrows)
{
    __shared__ alignas(16) ushort_t sx[64 * 136];
    __shared__ alignas(16) ushort_t st[64 * 136];
    const int tid  = threadIdx.x;
    const int wv   = tid >> 6, lane = tid & 63;
    const int col  = lane & 15, quad = lane >> 4;

    bf16x8 wf1[2][4], wf2[2][4];
    float rb1[2], rb2[2];
    #pragma unroll
    for (int nt = 0; nt < 2; ++nt) {
        int n = wv * 32 + nt * 16 + col;
        rb1[nt] = B1[n]; rb2[nt] = B2[n];
        #pragma unroll
        for (int kc = 0; kc < 4; ++kc)
            #pragma unroll
            for (int j = 0; j < 8; ++j) {
                int k = kc * 32 + quad * 8 + j;
                wf1[nt][kc][j] = (__bf16)W1[k * NF + n];
                wf2[nt][kc][j] = (__bf16)W2[k * NF + n];
            }
    }

    const int rbase = blockIdx.x * 64;
    for (int i = tid; i < 64 * 64; i += 256) {
        int r = i >> 6, c = i & 63;
        int gr = rbase + r;
        float2 v = (gr < nrows) ? *reinterpret_cast<const float2*>(&X[(size_t)gr * NF + 2 * c])
                                : make_float2(0.f, 0.f);
        reinterpret_cast<uint_t*>(sx)[r * 68 + c] = f2bf(v.x) | (f2bf(v.y) << 16);
    }
    __syncthreads();

    f32x4 acc[4][2];
    #pragma unroll
    for (int mt = 0; mt < 4; ++mt)
        #pragma unroll
        for (int nt = 0; nt < 2; ++nt)
            acc[mt][nt] = f32x4{rb1[nt], rb1[nt], rb1[nt], rb1[nt]};
    #pragma unroll
    for (int kc = 0; kc < 4; ++kc) {
        bf16x8 af[4];
        #pragma unroll
        for (int mt = 0; mt < 4; ++mt)
            af[mt] = *reinterpret_cast<const bf16x8*>(&sx[(mt * 16 + col) * 136 + kc * 32 + quad * 8]);
        #pragma unroll
        for (int mt = 0; mt < 4; ++mt)
            #pragma unroll
            for (int nt = 0; nt < 2; ++nt)
                acc[mt][nt] = __builtin_amdgcn_mfma_f32_16x16x32_bf16(af[mt], wf1[nt][kc], acc[mt][nt], 0, 0, 0);
    }
    #pragma unroll
    for (int mt = 0; mt < 4; ++mt)
        #pragma unroll
        for (int nt = 0; nt < 2; ++nt)
            #pragma unroll
            for (int r = 0; r < 4; ++r)
                st[(mt * 16 + quad * 4 + r) * 136 + wv * 32 + nt * 16 + col] =
                    (ushort_t)f2bf(ssp_f(acc[mt][nt][r]));
    __syncthreads();

    f32x4 acc2[4][2];
    #pragma unroll
    for (int mt = 0; mt < 4; ++mt)
        #pragma unroll
        for (int nt = 0; nt < 2; ++nt)
            acc2[mt][nt] = f32x4{rb2[nt], rb2[nt], rb2[nt], rb2[nt]};
    #pragma unroll
    for (int kc = 0; kc < 4; ++kc) {
        bf16x8 af[4];
        #pragma unroll
        for (int mt = 0; mt < 4; ++mt)
            af[mt] = *reinterpret_cast<const bf16x8*>(&st[(mt * 16 + col) * 136 + kc * 32 + quad * 8]);
        #pragma unroll
        for (int mt = 0; mt < 4; ++mt)
            #pragma unroll
            for (int nt = 0; nt < 2; ++nt)
                acc2[mt][nt] = __builtin_amdgcn_mfma_f32_16x16x32_bf16(af[mt], wf2[nt][kc], acc2[mt][nt], 0, 0, 0);
    }
    #pragma unroll
    for (int mt = 0; mt < 4; ++mt)
        #pragma unroll
        for (int nt = 0; nt < 2; ++nt)
            #pragma unroll
            for (int r = 0; r < 4; ++r) {
                int row = rbase + mt * 16 + quad * 4 + r;
                if (row < nrows) Y[(size_t)row * NF + wv * 32 + nt * 16 + col] = acc2[mt][nt][r];
            }
}

// ---------------- fused edge MLP (MFMA) + gather; epilogue: msg-store or atomic ----------------
// Grid MUST be 2000 blocks: 2000 * 4 waves * 5 iters * 16 edges = 640000.
template<bool ATOMIC>
__global__ __launch_bounds__(256) void k_edge(
    const int* __restrict__ esrc, const int* __restrict__ edst,
    const float* __restrict__ ew, const float* __restrict__ ea,
    const float* __restrict__ w1, const float* __restrict__ b1,
    const float* __restrict__ w2, const float* __restrict__ b2,
    const float* __restrict__ h, float* __restrict__ agg,
    __bf16* __restrict__ msg)
{
    __shared__ alignas(16) ushort_t w1f[16 * 64 * 8];   // 16 KB, frag = ntg*2+kc
    __shared__ alignas(16) ushort_t w2f[32 * 64 * 8];   // 32 KB, frag = ntg*4+kc
    __shared__ alignas(16) ushort_t st1[4][16 * 72];    // 9 KB, wave-private halves

    const int tid  = threadIdx.x;
    const int wv   = tid >> 6, lane = tid & 63;
    const int col  = lane & 15, quad = lane >> 4;

    for (int idx = tid; idx < 16 * 64; idx += 256) {
        int fr = idx >> 6, l = idx & 63;
        int ntg = fr >> 1, kc = fr & 1;
        int n = ntg * 16 + (l & 15), kb = kc * 32 + (l >> 4) * 8;
        ushort_t* d = &w1f[idx * 8];
        #pragma unroll
        for (int j = 0; j < 8; ++j) {
            int k = kb + j;
            d[j] = (ushort_t)((k < NB) ? f2bf(w1[k * NF + n]) : 0u);
        }
    }
    for (int idx = tid; idx < 32 * 64; idx += 256) {
        int fr = idx >> 6, l = idx & 63;
        int ntg = fr >> 2, kc = fr & 3;
        int n = ntg * 16 + (l & 15), kb = kc * 32 + (l >> 4) * 8;
        ushort_t* d = &w2f[idx * 8];
        #pragma unroll
        for (int j = 0; j < 8; ++j)
            d[j] = (ushort_t)f2bf(w2[(kb + j) * NF + n]);
    }
    float rb1[8], rb2[8];
    #pragma unroll
    for (int nt = 0; nt < 8; ++nt) { rb1[nt] = b1[nt * 16 + col]; rb2[nt] = b2[nt * 16 + col]; }
    __syncthreads();   // the only barrier

    ushort_t* myst = st1[wv];

    for (int it = 0; it < 5; ++it) {
        const int ebase = blockIdx.x * 320 + wv * 80 + it * 16;

        int srcv[4], dstv[4];
        float Cw[4];
        #pragma unroll
        for (int r = 0; r < 4; ++r) {
            int e = ebase + quad * 4 + r;
            srcv[r] = esrc[e];
            if (ATOMIC) dstv[r] = edst[e];
            Cw[r]   = 0.5f * (__cosf(ew[e] * 0.31415926535897931f) + 1.0f);
        }

        float hg[8][4];
        #pragma unroll
        for (int nt = 0; nt < 8; ++nt)
            #pragma unroll
            for (int r = 0; r < 4; ++r)
                hg[nt][r] = h[(size_t)srcv[r] * NF + nt * 16 + col];

        const float* erow = ea + (size_t)(ebase + col) * NB;
        bf16x8 af0, af1;
        #pragma unroll
        for (int p = 0; p < 4; ++p) {
            float2 v = *reinterpret_cast<const float2*>(erow + quad * 8 + 2 * p);
            af0[2 * p]     = (__bf16)v.x;
            af0[2 * p + 1] = (__bf16)v.y;
        }
        #pragma unroll
        for (int p = 0; p < 4; ++p) {
            int k = 32 + quad * 8 + 2 * p;
            float2 v = (k + 2 <= NB) ? *reinterpret_cast<const float2*>(erow + k)
                                     : make_float2(0.f, 0.f);
            af1[2 * p]     = (__bf16)v.x;
            af1[2 * p + 1] = (__bf16)v.y;
        }

        f32x4 acc2[8];
        #pragma unroll
        for (int nt = 0; nt < 8; ++nt) acc2[nt] = f32x4{rb2[nt], rb2[nt], rb2[nt], rb2[nt]};

        #pragma unroll
        for (int hf = 0; hf < 2; ++hf) {
            f32x4 acc1[4];
            #pragma unroll
            for (int nt = 0; nt < 4; ++nt) {
                int ntg = hf * 4 + nt;
                acc1[nt] = f32x4{rb1[ntg], rb1[ntg], rb1[ntg], rb1[ntg]};
                bf16x8 bw0 = *reinterpret_cast<const bf16x8*>(&w1f[((ntg * 2 + 0) * 64 + lane) * 8]);
                bf16x8 bw1 = *reinterpret_cast<const bf16x8*>(&w1f[((ntg * 2 + 1) * 64 + lane) * 8]);
                acc1[nt] = __builtin_amdgcn_mfma_f32_16x16x32_bf16(af0, bw0, acc1[nt], 0, 0, 0);
                acc1[nt] = __builtin_amdgcn_mfma_f32_16x16x32_bf16(af1, bw1, acc1[nt], 0, 0, 0);
            }
            #pragma unroll
            for (int nt = 0; nt < 4; ++nt)
                #pragma unroll
                for (int r = 0; r < 4; ++r)
                    myst[(quad * 4 + r) * 72 + nt * 16 + col] = (ushort_t)f2bf(ssp_f(acc1[nt][r]));
            bf16x8 a20 = *reinterpret_cast<const bf16x8*>(&myst[col * 72 + 0 * 32 + quad * 8]);
            bf16x8 a21 = *reinterpret_cast<const bf16x8*>(&myst[col * 72 + 1 * 32 + quad * 8]);
            #pragma unroll
            for (int nt = 0; nt < 8; ++nt) {
                bf16x8 b20 = *reinterpret_cast<const bf16x8*>(&w2f[((nt * 4 + hf * 2 + 0) * 64 + lane) * 8]);
                bf16x8 b21 = *reinterpret_cast<const bf16x8*>(&w2f[((nt * 4 + hf * 2 + 1) * 64 + lane) * 8]);
                acc2[nt] = __builtin_amdgcn_mfma_f32_16x16x32_bf16(a20, b20, acc2[nt], 0, 0, 0);
                acc2[nt] = __builtin_amdgcn_mfma_f32_16x16x32_bf16(a21, b21, acc2[nt], 0, 0, 0);
            }
        }

        #pragma unroll
        for (int nt = 0; nt < 8; ++nt)
            #pragma unroll
            for (int r = 0; r < 4; ++r) {
                float v = acc2[nt][r] * Cw[r] * hg[nt][r];
                if (ATOMIC) {
                    atomicAdd(&agg[(size_t)dstv[r] * NF + nt * 16 + col], v);
                } else {
                    msg[(size_t)(ebase + quad * 4 + r) * NF + nt * 16 + col] = (__bf16)v;
                }
            }
    }
}

extern "C" void kernel_launch(void* const* d_in, const int* in_sizes, int n_in,
                              void* d_out, int out_size, void* d_ws, size_t ws_size,
                              hipStream_t stream) {
    const float* x    = (const float*)d_in[0];
    const int*   eidx = (const int*)d_in[1];
    const float* ew   = (const float*)d_in[2];
    const float* ea   = (const float*)d_in[3];
    const float* w1   = (const float*)d_in[4];
    const float* b1   = (const float*)d_in[5];
    const float* w2   = (const float*)d_in[6];
    const float* b2   = (const float*)d_in[7];
    const float* l1w  = (const float*)d_in[8];
    const float* l2w  = (const float*)d_in[9];
    const float* l2b  = (const float*)d_in[10];
    const float* lw   = (const float*)d_in[11];
    const float* lb   = (const float*)d_in[12];
    (void)in_sizes; (void)n_in; (void)out_size;

    const int* esrc = eidx;
    const int* edst = eidx + NEDGES;

    char* p = (char*)d_ws;
    float* h    = (float*)p;                 p += (size_t)NNODES * NF * 4;   // 10.24 MB
    float* agg  = (float*)p;                 p += (size_t)NNODES * NF * 4;   // 10.24 MB
    int*   off  = (int*)p;                   p += (size_t)(NNODES + 4) * 4;
    int*   hist = (int*)p;                   p += (size_t)NNODES * 4;
    int*   cnt  = (int*)p;                   p += (size_t)NNODES * 4;
    int*   perm = (int*)p;                   p += (size_t)NEDGES * 4;        // 2.56 MB
    p = (char*)(((uintptr_t)p + 15) & ~(uintptr_t)15);
    __bf16* msg = (__bf16*)p;                p += (size_t)NEDGES * NF * 2;   // 163.84 MB
    const bool two_phase = ((size_t)(p - (char*)d_ws) <= ws_size);

    // h = x @ lin1_w (MFMA)
    hipLaunchKernelGGL(k_node1, dim3(313), dim3(256), 0, stream, x, l1w, h, NNODES);

    if (two_phase) {
        // build dst-grouped permutation
        hipLaunchKernelGGL(k_zero_small, dim3(157), dim3(256), 0, stream, hist, 2 * NNODES); // hist+cnt adjacent
        hipLaunchKernelGGL(k_hist, dim3(2500), dim3(256), 0, stream, edst, hist);
        hipLaunchKernelGGL(k_scan, dim3(1), dim3(1024), 0, stream, hist, off);
        hipLaunchKernelGGL(k_scatter, dim3(2500), dim3(256), 0, stream, edst, off, cnt, perm);
        // edge MLP -> msg (no atomics)
        hipLaunchKernelGGL((k_edge<false>), dim3(2000), dim3(256), 0, stream,
                           esrc, edst, ew, ea, w1, b1, w2, b2, h, agg, msg);
        // segment-sum msg -> agg (no atomics, fully writes agg)
        hipLaunchKernelGGL(k_agg, dim3(5000), dim3(256), 0, stream,
                           off, perm, (const ushort_t*)msg, agg);
    } else {
        // fallback: atomic scatter (round-5 behavior)
        hipLaunchKernelGGL(k_zero, dim3(2500), dim3(256), 0, stream, (float4*)agg);
        hipLaunchKernelGGL((k_edge<true>), dim3(2000), dim3(256), 0, stream,
                           esrc, edst, ew, ea, w1, b1, w2, b2, h, agg, msg);
    }

    // out = ssp(agg @ lin2_w + lin2_b) @ lin_w + lin_b (fused MFMA)
    hipLaunchKernelGGL(k_tail, dim3(313), dim3(256), 0, stream,
                       agg, l2w, l2b, lw, lb, (float*)d_out, NNODES);
}

// Round 7
// 558.989 us; speedup vs baseline: 1.1554x; 1.1554x over previous
//
#include <hip/hip_runtime.h>
#include <hip/hip_bf16.h>

#define NNODES 20000
#define NEDGES 640000
#define NB 50
#define NF 128
#define NBLK_SCAN 79   // ceil(20000/256)

typedef unsigned int uint_t;
typedef unsigned short ushort_t;

typedef __bf16 bf16x8 __attribute__((ext_vector_type(8)));
typedef float f32x4 __attribute__((ext_vector_type(4)));

// fast shifted softplus: hardware v_exp_f32 / v_log_f32
__device__ __forceinline__ float ssp_f(float x) {
    float t = __expf(-fabsf(x));
    return fmaxf(x, 0.0f) + __logf(1.0f + t) - 0.6931471805599453f;
}

// ---------------- zero hist + cnt ----------------
__global__ __launch_bounds__(256) void k_zero_small(int* __restrict__ p, int n) {
    int i = blockIdx.x * 256 + threadIdx.x;
    if (i < n) p[i] = 0;
}

// ---------------- histogram of dst ----------------
__global__ __launch_bounds__(256) void k_hist(const int* __restrict__ dst, int* __restrict__ hist) {
    int i = blockIdx.x * 256 + threadIdx.x;
    if (i < NEDGES) atomicAdd(&hist[dst[i]], 1);
}

// ---------------- hierarchical exclusive scan: blocksums ----------------
__global__ __launch_bounds__(256) void k_bsum(const int* __restrict__ hist, int* __restrict__ bsum) {
    __shared__ int ws[4];
    int i = blockIdx.x * 256 + threadIdx.x;
    int v = (i < NNODES) ? hist[i] : 0;
    #pragma unroll
    for (int s = 1; s < 64; s <<= 1) v += __shfl_xor(v, s, 64);
    if ((threadIdx.x & 63) == 0) ws[threadIdx.x >> 6] = v;
    __syncthreads();
    if (threadIdx.x == 0) bsum[blockIdx.x] = ws[0] + ws[1] + ws[2] + ws[3];
}

__global__ __launch_bounds__(64) void k_scan_b(const int* __restrict__ bsum, int* __restrict__ bbase) {
    if (threadIdx.x == 0) {
        int acc = 0;
        for (int b = 0; b < NBLK_SCAN; ++b) { bbase[b] = acc; acc += bsum[b]; }
    }
}

__global__ __launch_bounds__(256) void k_off(const int* __restrict__ hist, const int* __restrict__ bbase,
                                             int* __restrict__ off) {
    __shared__ int buf[256];
    int i = blockIdx.x * 256 + threadIdx.x;
    int v = (i < NNODES) ? hist[i] : 0;
    buf[threadIdx.x] = v;
    __syncthreads();
    #pragma unroll
    for (int s = 1; s < 256; s <<= 1) {
        int t = (threadIdx.x >= (unsigned)s) ? buf[threadIdx.x - s] : 0;
        __syncthreads();
        buf[threadIdx.x] += t;
        __syncthreads();
    }
    if (i < NNODES) off[i] = bbase[blockIdx.x] + buf[threadIdx.x] - v;
    if (i == NNODES) off[NNODES] = NEDGES;
}

// ---------------- scatter: dst-grouped perm + pre-gathered src + cutoff ----------------
__global__ __launch_bounds__(256) void k_scatter(const int* __restrict__ src, const int* __restrict__ dst,
                                                 const float* __restrict__ ew,
                                                 const int* __restrict__ off, int* __restrict__ cnt,
                                                 int* __restrict__ perm, int* __restrict__ srcs,
                                                 float* __restrict__ Cs) {
    int i = blockIdx.x * 256 + threadIdx.x;
    if (i < NEDGES) {
        int d = dst[i];
        int pos = off[d] + atomicAdd(&cnt[d], 1);
        perm[pos] = i;
        srcs[pos] = src[i];
        Cs[pos]   = 0.5f * (__cosf(ew[i] * 0.31415926535897931f) + 1.0f);
    }
}

// ---------------- node GEMM: Y = X @ W  (MFMA, 64-row tile) ----------------
__global__ __launch_bounds__(256) void k_node1(const float* __restrict__ X,
                                               const float* __restrict__ W,
                                               float* __restrict__ Y, int nrows)
{
    __shared__ alignas(16) __bf16 sx[64 * 136];
    const int tid  = threadIdx.x;
    const int wv   = tid >> 6, lane = tid & 63;
    const int col  = lane & 15, quad = lane >> 4;

    bf16x8 wf[2][4];
    #pragma unroll
    for (int nt = 0; nt < 2; ++nt) {
        int n = wv * 32 + nt * 16 + col;
        #pragma unroll
        for (int kc = 0; kc < 4; ++kc)
            #pragma unroll
            for (int j = 0; j < 8; ++j)
                wf[nt][kc][j] = (__bf16)W[(kc * 32 + quad * 8 + j) * NF + n];
    }

    const int rbase = blockIdx.x * 64;
    for (int i = tid; i < 64 * 64; i += 256) {
        int r = i >> 6, c = i & 63;
        int gr = rbase + r;
        float2 v = (gr < nrows) ? *reinterpret_cast<const float2*>(&X[(size_t)gr * NF + 2 * c])
                                : make_float2(0.f, 0.f);
        sx[r * 136 + 2 * c]     = (__bf16)v.x;
        sx[r * 136 + 2 * c + 1] = (__bf16)v.y;
    }
    __syncthreads();

    f32x4 acc[4][2] = {};
    #pragma unroll
    for (int kc = 0; kc < 4; ++kc) {
        bf16x8 af[4];
        #pragma unroll
        for (int mt = 0; mt < 4; ++mt)
            af[mt] = *reinterpret_cast<const bf16x8*>(&sx[(mt * 16 + col) * 136 + kc * 32 + quad * 8]);
        #pragma unroll
        for (int mt = 0; mt < 4; ++mt)
            #pragma unroll
            for (int nt = 0; nt < 2; ++nt)
                acc[mt][nt] = __builtin_amdgcn_mfma_f32_16x16x32_bf16(af[mt], wf[nt][kc], acc[mt][nt], 0, 0, 0);
    }
    #pragma unroll
    for (int mt = 0; mt < 4; ++mt)
        #pragma unroll
        for (int nt = 0; nt < 2; ++nt)
            #pragma unroll
            for (int r = 0; r < 4; ++r) {
                int row = rbase + mt * 16 + quad * 4 + r;
                if (row < nrows) Y[(size_t)row * NF + wv * 32 + nt * 16 + col] = acc[mt][nt][r];
            }
}

// ---------------- fused tail: out = ssp(X @ W1 + b1) @ W2 + b2 ----------------
__global__ __launch_bounds__(256) void k_tail(const float* __restrict__ X,
                                              const float* __restrict__ W1, const float* __restrict__ B1,
                                              const float* __restrict__ W2, const float* __restrict__ B2,
                                              float* __restrict__ Y, int nrows)
{
    __shared__ alignas(16) __bf16 sx[64 * 136];
    __shared__ alignas(16) __bf16 st[64 * 136];
    const int tid  = threadIdx.x;
    const int wv   = tid >> 6, lane = tid & 63;
    const int col  = lane & 15, quad = lane >> 4;

    bf16x8 wf1[2][4], wf2[2][4];
    float rb1[2], rb2[2];
    #pragma unroll
    for (int nt = 0; nt < 2; ++nt) {
        int n = wv * 32 + nt * 16 + col;
        rb1[nt] = B1[n]; rb2[nt] = B2[n];
        #pragma unroll
        for (int kc = 0; kc < 4; ++kc)
            #pragma unroll
            for (int j = 0; j < 8; ++j) {
                int k = kc * 32 + quad * 8 + j;
                wf1[nt][kc][j] = (__bf16)W1[k * NF + n];
                wf2[nt][kc][j] = (__bf16)W2[k * NF + n];
            }
    }

    const int rbase = blockIdx.x * 64;
    for (int i = tid; i < 64 * 64; i += 256) {
        int r = i >> 6, c = i & 63;
        int gr = rbase + r;
        float2 v = (gr < nrows) ? *reinterpret_cast<const float2*>(&X[(size_t)gr * NF + 2 * c])
                                : make_float2(0.f, 0.f);
        sx[r * 136 + 2 * c]     = (__bf16)v.x;
        sx[r * 136 + 2 * c + 1] = (__bf16)v.y;
    }
    __syncthreads();

    f32x4 acc[4][2];
    #pragma unroll
    for (int mt = 0; mt < 4; ++mt)
        #pragma unroll
        for (int nt = 0; nt < 2; ++nt)
            acc[mt][nt] = f32x4{rb1[nt], rb1[nt], rb1[nt], rb1[nt]};
    #pragma unroll
    for (int kc = 0; kc < 4; ++kc) {
        bf16x8 af[4];
        #pragma unroll
        for (int mt = 0; mt < 4; ++mt)
            af[mt] = *reinterpret_cast<const bf16x8*>(&sx[(mt * 16 + col) * 136 + kc * 32 + quad * 8]);
        #pragma unroll
        for (int mt = 0; mt < 4; ++mt)
            #pragma unroll
            for (int nt = 0; nt < 2; ++nt)
                acc[mt][nt] = __builtin_amdgcn_mfma_f32_16x16x32_bf16(af[mt], wf1[nt][kc], acc[mt][nt], 0, 0, 0);
    }
    #pragma unroll
    for (int mt = 0; mt < 4; ++mt)
        #pragma unroll
        for (int nt = 0; nt < 2; ++nt)
            #pragma unroll
            for (int r = 0; r < 4; ++r)
                st[(mt * 16 + quad * 4 + r) * 136 + wv * 32 + nt * 16 + col] = (__bf16)ssp_f(acc[mt][nt][r]);
    __syncthreads();

    f32x4 acc2[4][2];
    #pragma unroll
    for (int mt = 0; mt < 4; ++mt)
        #pragma unroll
        for (int nt = 0; nt < 2; ++nt)
            acc2[mt][nt] = f32x4{rb2[nt], rb2[nt], rb2[nt], rb2[nt]};
    #pragma unroll
    for (int kc = 0; kc < 4; ++kc) {
        bf16x8 af[4];
        #pragma unroll
        for (int mt = 0; mt < 4; ++mt)
            af[mt] = *reinterpret_cast<const bf16x8*>(&st[(mt * 16 + col) * 136 + kc * 32 + quad * 8]);
        #pragma unroll
        for (int mt = 0; mt < 4; ++mt)
            #pragma unroll
            for (int nt = 0; nt < 2; ++nt)
                acc2[mt][nt] = __builtin_amdgcn_mfma_f32_16x16x32_bf16(af[mt], wf2[nt][kc], acc2[mt][nt], 0, 0, 0);
    }
    #pragma unroll
    for (int mt = 0; mt < 4; ++mt)
        #pragma unroll
        for (int nt = 0; nt < 2; ++nt)
            #pragma unroll
            for (int r = 0; r < 4; ++r) {
                int row = rbase + mt * 16 + quad * 4 + r;
                if (row < nrows) Y[(size_t)row * NF + wv * 32 + nt * 16 + col] = acc2[mt][nt][r];
            }
}

// ---------------- single-pass CSR edge kernel: MLP + gather + per-node reduce ----------------
// Grid MUST be 1000 blocks x 4 waves = 4000 waves; each wave owns 5 nodes
// (4000*5 = 20000). For each node: walk its dst-sorted edge segment in
// 16-edge MFMA tiles, accumulate in registers, shuffle-reduce, write agg row.
// No atomics, no intermediate msg buffer.
__global__ __launch_bounds__(256) void k_edge_csr(
    const int* __restrict__ off, const int* __restrict__ perm,
    const int* __restrict__ srcs, const float* __restrict__ Cs,
    const float* __restrict__ ea,
    const float* __restrict__ w1, const float* __restrict__ b1,
    const float* __restrict__ w2, const float* __restrict__ b2,
    const float* __restrict__ h, float* __restrict__ agg)
{
    __shared__ alignas(16) __bf16 w1f[16 * 64 * 8];   // 16 KB, frag = ntg*2+kc
    __shared__ alignas(16) __bf16 w2f[32 * 64 * 8];   // 32 KB, frag = ntg*4+kc
    __shared__ alignas(16) __bf16 st1[4][16 * 72];    // 9 KB, wave-private halves

    const int tid  = threadIdx.x;
    const int wv   = tid >> 6, lane = tid & 63;
    const int col  = lane & 15, quad = lane >> 4;

    // stage weight B-fragments (one-time)
    for (int idx = tid; idx < 16 * 64; idx += 256) {
        int fr = idx >> 6, l = idx & 63;
        int ntg = fr >> 1, kc = fr & 1;
        int n = ntg * 16 + (l & 15), kb = kc * 32 + (l >> 4) * 8;
        __bf16* d = &w1f[idx * 8];
        #pragma unroll
        for (int j = 0; j < 8; ++j) {
            int k = kb + j;
            d[j] = (__bf16)((k < NB) ? w1[k * NF + n] : 0.0f);
        }
    }
    for (int idx = tid; idx < 32 * 64; idx += 256) {
        int fr = idx >> 6, l = idx & 63;
        int ntg = fr >> 2, kc = fr & 3;
        int n = ntg * 16 + (l & 15), kb = kc * 32 + (l >> 4) * 8;
        __bf16* d = &w2f[idx * 8];
        #pragma unroll
        for (int j = 0; j < 8; ++j)
            d[j] = (__bf16)w2[(kb + j) * NF + n];
    }
    float rb1[8], rb2[8];
    #pragma unroll
    for (int nt = 0; nt < 8; ++nt) { rb1[nt] = b1[nt * 16 + col]; rb2[nt] = b2[nt * 16 + col]; }
    __syncthreads();   // the only barrier

    __bf16* myst = st1[wv];
    const int gw = blockIdx.x * 4 + wv;   // 0..3999

    for (int ni = 0; ni < 5; ++ni) {
        const int n = gw * 5 + ni;        // < 20000 always
        const int s = off[n], eend = off[n + 1];

        float pacc[8] = {0.f, 0.f, 0.f, 0.f, 0.f, 0.f, 0.f, 0.f};

        for (int base = s; base < eend; base += 16) {
            // per-lane slot (col dimension); lanes 16-63 duplicate cols 0-15
            int pos  = base + col;
            int lpos = min(pos, NEDGES - 1);
            int eidc = perm[lpos];
            int srcc = srcs[lpos];
            float Cv = (pos < eend) ? Cs[lpos] : 0.0f;

            // per-row (quad*4+r) metadata via cross-lane pull
            int   src_r[4];
            float Cw[4];
            #pragma unroll
            for (int r = 0; r < 4; ++r) {
                int sl = quad * 4 + r;
                src_r[r] = __shfl(srcc, sl, 64);
                Cw[r]    = __shfl(Cv,   sl, 64);
            }

            // hoisted gathers (hide behind the MLP)
            float hg[8][4];
            #pragma unroll
            for (int nt = 0; nt < 8; ++nt)
                #pragma unroll
                for (int r = 0; r < 4; ++r)
                    hg[nt][r] = h[(size_t)src_r[r] * NF + nt * 16 + col];

            // layer-1 A-frags from ea[eidc] (row = col)
            const float* erow = ea + (size_t)eidc * NB;
            bf16x8 af0, af1;
            #pragma unroll
            for (int p = 0; p < 4; ++p) {
                float2 v = *reinterpret_cast<const float2*>(erow + quad * 8 + 2 * p);
                af0[2 * p]     = (__bf16)v.x;
                af0[2 * p + 1] = (__bf16)v.y;
            }
            #pragma unroll
            for (int p = 0; p < 4; ++p) {
                int k = 32 + quad * 8 + 2 * p;
                float2 v = (k + 2 <= NB) ? *reinterpret_cast<const float2*>(erow + k)
                                         : make_float2(0.f, 0.f);
                af1[2 * p]     = (__bf16)v.x;
                af1[2 * p + 1] = (__bf16)v.y;
            }

            f32x4 acc2[8];
            #pragma unroll
            for (int nt = 0; nt < 8; ++nt) acc2[nt] = f32x4{rb2[nt], rb2[nt], rb2[nt], rb2[nt]};

            #pragma unroll
            for (int hf = 0; hf < 2; ++hf) {
                f32x4 acc1[4];
                #pragma unroll
                for (int nt = 0; nt < 4; ++nt) {
                    int ntg = hf * 4 + nt;
                    acc1[nt] = f32x4{rb1[ntg], rb1[ntg], rb1[ntg], rb1[ntg]};
                    bf16x8 bw0 = *reinterpret_cast<const bf16x8*>(&w1f[((ntg * 2 + 0) * 64 + lane) * 8]);
                    bf16x8 bw1 = *reinterpret_cast<const bf16x8*>(&w1f[((ntg * 2 + 1) * 64 + lane) * 8]);
                    acc1[nt] = __builtin_amdgcn_mfma_f32_16x16x32_bf16(af0, bw0, acc1[nt], 0, 0, 0);
                    acc1[nt] = __builtin_amdgcn_mfma_f32_16x16x32_bf16(af1, bw1, acc1[nt], 0, 0, 0);
                }
                #pragma unroll
                for (int nt = 0; nt < 4; ++nt)
                    #pragma unroll
                    for (int r = 0; r < 4; ++r)
                        myst[(quad * 4 + r) * 72 + nt * 16 + col] = (__bf16)ssp_f(acc1[nt][r]);
                bf16x8 a20 = *reinterpret_cast<const bf16x8*>(&myst[col * 72 + 0 * 32 + quad * 8]);
                bf16x8 a21 = *reinterpret_cast<const bf16x8*>(&myst[col * 72 + 1 * 32 + quad * 8]);
                #pragma unroll
                for (int nt = 0; nt < 8; ++nt) {
                    bf16x8 b20 = *reinterpret_cast<const bf16x8*>(&w2f[((nt * 4 + hf * 2 + 0) * 64 + lane) * 8]);
                    bf16x8 b21 = *reinterpret_cast<const bf16x8*>(&w2f[((nt * 4 + hf * 2 + 1) * 64 + lane) * 8]);
                    acc2[nt] = __builtin_amdgcn_mfma_f32_16x16x32_bf16(a20, b20, acc2[nt], 0, 0, 0);
                    acc2[nt] = __builtin_amdgcn_mfma_f32_16x16x32_bf16(a21, b21, acc2[nt], 0, 0, 0);
                }
            }

            // accumulate this tile's contribution (padded rows have Cw=0)
            #pragma unroll
            for (int nt = 0; nt < 8; ++nt)
                #pragma unroll
                for (int r = 0; r < 4; ++r) {
                    float t = Cw[r] * hg[nt][r];
                    pacc[nt] = fmaf(acc2[nt][r], t, pacc[nt]);
                }
        }

        // cross-quad reduce (sum the 4 row-groups) and write the agg row
        #pragma unroll
        for (int nt = 0; nt < 8; ++nt) {
            float v = pacc[nt];
            v += __shfl_xor(v, 16, 64);
            v += __shfl_xor(v, 32, 64);
            if (lane < 16) agg[(size_t)n * NF + nt * 16 + lane] = v;
        }
    }
}

extern "C" void kernel_launch(void* const* d_in, const int* in_sizes, int n_in,
                              void* d_out, int out_size, void* d_ws, size_t ws_size,
                              hipStream_t stream) {
    const float* x    = (const float*)d_in[0];
    const int*   eidx = (const int*)d_in[1];
    const float* ew   = (const float*)d_in[2];
    const float* ea   = (const float*)d_in[3];
    const float* w1   = (const float*)d_in[4];
    const float* b1   = (const float*)d_in[5];
    const float* w2   = (const float*)d_in[6];
    const float* b2   = (const float*)d_in[7];
    const float* l1w  = (const float*)d_in[8];
    const float* l2w  = (const float*)d_in[9];
    const float* l2b  = (const float*)d_in[10];
    const float* lw   = (const float*)d_in[11];
    const float* lb   = (const float*)d_in[12];
    (void)in_sizes; (void)n_in; (void)out_size; (void)ws_size;

    const int* esrc = eidx;
    const int* edst = eidx + NEDGES;

    char* p = (char*)d_ws;
    float* h    = (float*)p;  p += (size_t)NNODES * NF * 4;      // 10.24 MB
    float* agg  = (float*)p;  p += (size_t)NNODES * NF * 4;      // 10.24 MB
    int*   off  = (int*)p;    p += (size_t)(NNODES + 4) * 4;
    int*   hist = (int*)p;    p += (size_t)NNODES * 4;
    int*   cnt  = (int*)p;    p += (size_t)NNODES * 4;
    int*   bsum = (int*)p;    p += 128 * 4;
    int*   bbase= (int*)p;    p += 128 * 4;
    int*   perm = (int*)p;    p += (size_t)NEDGES * 4;           // 2.56 MB
    int*   srcs = (int*)p;    p += (size_t)NEDGES * 4;           // 2.56 MB
    float* Cs   = (float*)p;  p += (size_t)NEDGES * 4;           // 2.56 MB

    // h = x @ lin1_w (MFMA)
    hipLaunchKernelGGL(k_node1, dim3(313), dim3(256), 0, stream, x, l1w, h, NNODES);

    // dst-sorted CSR build (hist -> hierarchical scan -> scatter w/ pre-gather)
    hipLaunchKernelGGL(k_zero_small, dim3(157), dim3(256), 0, stream, hist, 2 * NNODES); // hist+cnt adjacent
    hipLaunchKernelGGL(k_hist, dim3(2500), dim3(256), 0, stream, edst, hist);
    hipLaunchKernelGGL(k_bsum, dim3(NBLK_SCAN), dim3(256), 0, stream, hist, bsum);
    hipLaunchKernelGGL(k_scan_b, dim3(1), dim3(64), 0, stream, bsum, bbase);
    hipLaunchKernelGGL(k_off, dim3(NBLK_SCAN), dim3(256), 0, stream, hist, bbase, off);
    hipLaunchKernelGGL(k_scatter, dim3(2500), dim3(256), 0, stream,
                       esrc, edst, ew, off, cnt, perm, srcs, Cs);

    // single-pass fused edge MLP + CFConv + per-node reduce (no atomics)
    hipLaunchKernelGGL(k_edge_csr, dim3(1000), dim3(256), 0, stream,
                       off, perm, srcs, Cs, ea, w1, b1, w2, b2, h, agg);

    // out = ssp(agg @ lin2_w + lin2_b) @ lin_w + lin_b (fused MFMA)
    hipLaunchKernelGGL(k_tail, dim3(313), dim3(256), 0, stream,
                       agg, l2w, l2b, lw, lb, (float*)d_out, NNODES);
}